// Round 7
// baseline (349.152 us; speedup 1.0000x reference)
//
#include <hip/hip_runtime.h>
#include <hip/hip_bf16.h>
#include <stdint.h>

// LSTM cell fused kernel for MI355X (gfx950).
// gates = [X | h_prev] @ [W_ih | W_hh]^T  (one GEMM, M=8192, N=4096, K=2048)
// Round 7 (third submit of the R5 design; R5/R6 benches died to container
// acquisition failures with no kernel-attributable evidence — source audited
// twice for deadlock/OOB/alignment/race, all clean):
// 256x256 tile, 8 waves, BK=64, REGISTER-STAGED true double buffer.
// No global_load_lds (R3/R4 showed its outstanding-DMA queue serializes every
// phase's ds_reads): tile t+1 is loaded global->VGPR (two 64 B half-rounds per
// thread), ds_written to the ALT buffer while tile t computes from CUR, one
// __syncthreads per K-tile. LDS rows are 128 B with slot^=(row&7) XOR swizzle
// (applied at both ds_write and ds_read; 2-way = free). LSTM epilogue fused.

typedef __attribute__((ext_vector_type(8))) __bf16 bf16x8;
typedef __attribute__((ext_vector_type(8))) unsigned short u16x8;
typedef __attribute__((ext_vector_type(4))) float f32x4;
typedef __attribute__((ext_vector_type(4))) unsigned int u32x4;

__device__ __forceinline__ unsigned short f2bf(float f) {
  union { float f; unsigned int u; } v; v.f = f;
  unsigned int r = v.u + 0x7FFFu + ((v.u >> 16) & 1u);  // RNE
  return (unsigned short)(r >> 16);
}

// Linear f32 -> bf16 conversion of all four operand tensors, one dispatch.
__global__ void cvt_all(const float* __restrict__ s0, const float* __restrict__ s1,
                        const float* __restrict__ s2, const float* __restrict__ s3,
                        unsigned short* __restrict__ d0, unsigned short* __restrict__ d1,
                        unsigned short* __restrict__ d2, unsigned short* __restrict__ d3) {
  const float* src; unsigned short* dst; int n8;
  if (blockIdx.y == 0)      { src = s0; dst = d0; n8 = 8192 * 128; }
  else if (blockIdx.y == 1) { src = s1; dst = d1; n8 = 8192 * 128; }
  else if (blockIdx.y == 2) { src = s2; dst = d2; n8 = 4096 * 128; }
  else                      { src = s3; dst = d3; n8 = 4096 * 128; }
  int i = blockIdx.x * blockDim.x + threadIdx.x;
  int stride = gridDim.x * blockDim.x;
  for (; i < n8; i += stride) {
    float4 a = ((const float4*)src)[2 * i];
    float4 b = ((const float4*)src)[2 * i + 1];
    u16x8 o;
    o[0] = f2bf(a.x); o[1] = f2bf(a.y); o[2] = f2bf(a.z); o[3] = f2bf(a.w);
    o[4] = f2bf(b.x); o[5] = f2bf(b.y); o[6] = f2bf(b.z); o[7] = f2bf(b.w);
    *(u16x8*)&dst[(size_t)i * 8] = o;
  }
}

// Load one K-half (32 elems = 64 B) of this thread's staging row into stg.
// Threads 0..255 stage A rows (row_l = tid), 256..511 stage B rows.
#define LOADHALF(T, KS) do {                                                   \
    const unsigned short* bsrc_; int kk_;                                      \
    if ((T) < 16) { bsrc_ = isB ? Wihb : Xb; kk_ = (T) * 64; }                 \
    else          { bsrc_ = isB ? Whhb : Hb; kk_ = ((T) - 16) * 64; }          \
    const unsigned short* p_ = bsrc_ + (size_t)grow_ws * 1024 + kk_ + (KS) * 32;\
    stg[0] = *(const u32x4*)(p_);                                              \
    stg[1] = *(const u32x4*)(p_ + 8);                                          \
    stg[2] = *(const u32x4*)(p_ + 16);                                         \
    stg[3] = *(const u32x4*)(p_ + 24);                                         \
  } while (0)

// ds_write the 4 staged 16 B chunks to buffer BUF, K-half KS, XOR-swizzled.
#define DSWRITEHALF(BUF, KS) do {                                              \
    char* wb_ = (BUF) + isB * 32768 + row_l * 128;                             \
    *(u32x4*)(wb_ + ((((KS) * 4 + 0) ^ swz_) * 16)) = stg[0];                  \
    *(u32x4*)(wb_ + ((((KS) * 4 + 1) ^ swz_) * 16)) = stg[1];                  \
    *(u32x4*)(wb_ + ((((KS) * 4 + 2) ^ swz_) * 16)) = stg[2];                  \
    *(u32x4*)(wb_ + ((((KS) * 4 + 3) ^ swz_) * 16)) = stg[3];                  \
  } while (0)

// One C-quadrant (KS = K-half, MH = m-half): 8 ds_read_b128 + 16 MFMA.
#define QUADRANT(CUR, KS, MH) do {                                             \
    bf16x8 af_[4], bf_[4];                                                     \
    _Pragma("unroll")                                                          \
    for (int m2 = 0; m2 < 4; ++m2) {                                           \
      const int ra_ = wr * 128 + ((MH) * 4 + m2) * 16 + l15;                   \
      af_[m2] = *(const bf16x8*)((CUR) + ra_ * 128 +                           \
                                 ((((KS) * 4 + l4) ^ (ra_ & 7)) * 16));        \
    }                                                                          \
    _Pragma("unroll")                                                          \
    for (int n_ = 0; n_ < 4; ++n_) {                                           \
      const int rb_ = wc * 64 + n_ * 16 + l15;                                 \
      bf_[n_] = *(const bf16x8*)((CUR) + 32768 + rb_ * 128 +                   \
                                 ((((KS) * 4 + l4) ^ (rb_ & 7)) * 16));        \
    }                                                                          \
    _Pragma("unroll")                                                          \
    for (int m2 = 0; m2 < 4; ++m2)                                             \
      _Pragma("unroll")                                                        \
      for (int n_ = 0; n_ < 4; ++n_)                                           \
        acc[(MH) * 4 + m2][n_] = __builtin_amdgcn_mfma_f32_16x16x32_bf16(      \
            af_[m2], bf_[n_], acc[(MH) * 4 + m2][n_], 0, 0, 0);                \
  } while (0)

__global__ __launch_bounds__(512, 2) void lstm_fused(
    const unsigned short* __restrict__ Xb, const unsigned short* __restrict__ Hb,
    const unsigned short* __restrict__ Wihb, const unsigned short* __restrict__ Whhb,
    const float* __restrict__ bih, const float* __restrict__ bhh,
    const float* __restrict__ cprev, float* __restrict__ out) {
  // two 64 KB tile buffers (A 32K + B 32K each); epilogue reuses all 128 KB
  __shared__ __align__(16) char smem[131072];

  const int tid = threadIdx.x;
  const int lane = tid & 63;
  const int wid = tid >> 6;
  const int wr = wid >> 2;   // 0..1 : wave row (128 rows)
  const int wc = wid & 3;    // 0..3 : wave col (64 cols = one gate)
  const int l15 = lane & 15;
  const int l4 = lane >> 4;

  // bijective XCD-chunked swizzle (512 % 8 == 0)
  const int bid = blockIdx.x;
  const int tile_id = (bid & 7) * 64 + (bid >> 3);
  const int m0 = (tile_id >> 4) * 256;  // batch-row tile
  const int h0 = (tile_id & 15) * 64;   // hidden-unit tile (x 4 gates)

  // staging role: threads 0..255 -> A row row_l; 256..511 -> B row row_l
  const int row_l = tid & 255;
  const int isB = tid >> 8;
  const int swz_ = row_l & 7;
  const int grow_ws = isB ? ((row_l >> 6) * 1024 + h0 + (row_l & 63))
                          : (m0 + row_l);

  f32x4 acc[8][4];
#pragma unroll
  for (int m = 0; m < 8; ++m)
#pragma unroll
    for (int n = 0; n < 4; ++n) {
      f32x4 z = {0.f, 0.f, 0.f, 0.f};
      acc[m][n] = z;
    }

  u32x4 stg[4];

  // Prologue: stage tile 0 into buf0; issue L0 of tile 1.
  LOADHALF(0, 0); DSWRITEHALF(smem, 0);
  LOADHALF(0, 1); DSWRITEHALF(smem, 1);
  LOADHALF(1, 0);
  __syncthreads();

#pragma unroll 1
  for (int t = 0; t < 32; ++t) {
    char* cur = smem + (t & 1) * 65536;
    char* alt = smem + ((t & 1) ^ 1) * 65536;
    QUADRANT(cur, 0, 0);
    QUADRANT(cur, 0, 1);
    if (t < 31) {
      DSWRITEHALF(alt, 0);     // L0(t+1): issued one full tile ago
      LOADHALF(t + 1, 1);      // L1(t+1): flies under quadrants 2,3
    }
    QUADRANT(cur, 1, 0);
    QUADRANT(cur, 1, 1);
    if (t < 31) {
      DSWRITEHALF(alt, 1);
      if (t < 30) LOADHALF(t + 2, 0);  // flies under barrier + next quadrants
      __syncthreads();
    }
  }

  // ---- fused LSTM epilogue: exchange acc via LDS, 2 row-phases of 128 ----
  __syncthreads();
#pragma unroll
  for (int ph = 0; ph < 2; ++ph) {
    if (ph) __syncthreads();
    if (wr == ph) {
#pragma unroll
      for (int m = 0; m < 8; ++m)
#pragma unroll
        for (int n = 0; n < 4; ++n)
          *(f32x4*)(smem + (((wc * 8 + m) * 4 + n) * 64 + lane) * 16) = acc[m][n];
    }
    __syncthreads();
#pragma unroll
    for (int q = 0; q < 4; ++q) {
      f32x4 vg[4];
#pragma unroll
      for (int g = 0; g < 4; ++g)
        vg[g] = *(const f32x4*)(smem + (((g * 8 + wid) * 4 + q) * 64 + lane) * 16);
      const int gcol = h0 + q * 16 + l15;
      const float b0 = bih[gcol]        + bhh[gcol];
      const float b1 = bih[1024 + gcol] + bhh[1024 + gcol];
      const float b2 = bih[2048 + gcol] + bhh[2048 + gcol];
      const float b3 = bih[3072 + gcol] + bhh[3072 + gcol];
#pragma unroll
      for (int j = 0; j < 4; ++j) {
        const size_t row = (size_t)(m0 + ph * 128 + wid * 16 + l4 * 4 + j);
        const float vi = vg[0][j] + b0;
        const float vf = vg[1][j] + b1;
        const float vgt = vg[2][j] + b2;
        const float vo = vg[3][j] + b3;
        const float si = 1.f / (1.f + __expf(-vi));
        const float sf = 1.f / (1.f + __expf(-vf));
        const float tg = tanhf(vgt);
        const float so = 1.f / (1.f + __expf(-vo));
        const float cp = cprev[row * 1024 + gcol];
        const float ct = sf * cp + si * tg;
        const float ht = so * tanhf(ct);
        out[row * 1024 + gcol] = ht;                 // h_t
        out[8388608 + row * 1024 + gcol] = ct;       // c_t
      }
    }
  }
}

extern "C" void kernel_launch(void* const* d_in, const int* in_sizes, int n_in,
                              void* d_out, int out_size, void* d_ws, size_t ws_size,
                              hipStream_t stream) {
  const float* input  = (const float*)d_in[0];
  const float* h_prev = (const float*)d_in[1];
  const float* c_prev = (const float*)d_in[2];
  const float* W_ih   = (const float*)d_in[3];
  const float* b_ih   = (const float*)d_in[4];
  const float* W_hh   = (const float*)d_in[5];
  const float* b_hh   = (const float*)d_in[6];
  float* out = (float*)d_out;

  unsigned short* Xb   = (unsigned short*)d_ws;
  unsigned short* Hb   = Xb + (size_t)8192 * 1024;
  unsigned short* Wihb = Hb + (size_t)8192 * 1024;
  unsigned short* Whhb = Wihb + (size_t)4096 * 1024;
  // ws use: (8192+8192+4096+4096)*1024*2 = 50,331,648 bytes

  dim3 cgrid(1024, 4);
  cvt_all<<<cgrid, 256, 0, stream>>>(input, h_prev, W_ih, W_hh, Xb, Hb, Wihb, Whhb);

  lstm_fused<<<512, 512, 0, stream>>>(Xb, Hb, Wihb, Whhb, b_ih, b_hh, c_prev, out);
}